// Round 11
// baseline (101.984 us; speedup 1.0000x reference)
//
#include <hip/hip_runtime.h>

typedef __attribute__((ext_vector_type(8))) short short8;
typedef __attribute__((ext_vector_type(4))) float f32x4;
typedef unsigned short u16;

__device__ __forceinline__ u16 f2bf(float f) {
    unsigned u = __builtin_bit_cast(unsigned, f);
    unsigned r = u + 0x7fffu + ((u >> 16) & 1u);
    return (u16)(r >> 16);
}
__device__ __forceinline__ unsigned pkbf(float lo, float hi) {
    unsigned r;
    asm("v_cvt_pk_bf16_f32 %0, %1, %2" : "=v"(r) : "v"(lo), "v"(hi));
    return r;
}

// ---------------- K0: prep (out=cpose/0, pack weights) -----------------------
__global__ __launch_bounds__(256) void k0_prep(
    const float* __restrict__ z, const float* __restrict__ w1,
    const float* __restrict__ w2, const float* __restrict__ wfc1,
    const float* __restrict__ wpose, const float* __restrict__ bpose,
    const float* __restrict__ wfc2, const float* __restrict__ bfc2,
    float* __restrict__ out, u16* __restrict__ w1p, u16* __restrict__ w2p,
    u16* __restrict__ fc1T)
{
    int gt = blockIdx.x * 256 + threadIdx.x;   // 0..16383

    {   // pose branch + b_fc2 constant (redundant per thread), init heat
        float zz = z[0];
        float s = bfc2[0];
        #pragma unroll
        for (int j = 0; j < 16; ++j) {
            float p = fmaxf(zz * wpose[j] + bpose[j], 0.f);
            s += p * wfc2[128 + j];
        }
        int y = gt >> 7, x = gt & 127;
        bool interior = (y >= 16) && (y < 112) && (x >= 16) && (x < 112);
        out[gt] = interior ? s : 0.f;
    }

    if (gt < 2560) {                           // w1 pack: [5 ksteps][64 lanes][8]
        int l = (gt >> 3) & 63, j = gt & 7, s = gt >> 9;
        int o = l & 15, bq = l >> 4;
        u16 v = 0;
        if (bq < 3) {
            int dx = bq * 4 + (j & 3);
            int dy = -1;
            if (s < 4) dy = 2 * s + (j >> 2);
            else if (j < 4) dy = 8;
            if (dy >= 0 && dx <= 8) v = f2bf(w1[o * 81 + dy * 9 + dx]);
        }
        w1p[gt] = v;
    }
    if (gt < 6656) {                           // w2 pack: [13][64][8]
        int l = (gt >> 3) & 63, j = gt & 7, s = gt >> 9;
        int o = l & 15, bq = l >> 4;
        int dy, dx, c8; bool valid = true;
        if (s < 5)       { dy = s;     dx = bq >> 1;       c8 = bq & 1; }
        else if (s < 10) { dy = s - 5; dx = 2 + (bq >> 1); c8 = bq & 1; }
        else { dy = (s - 10) + 3 * (bq & 1); dx = 4; c8 = bq >> 1; valid = (dy <= 4); }
        int ci = c8 * 8 + j;
        w2p[gt] = valid ? f2bf(w2[o * 400 + ci * 25 + dy * 5 + dx]) : (u16)0;
    }
    {                                          // fc1 transpose-pack: [128 n][1024 k]
        int base = gt * 8;
        int n = base >> 10, kk = base & 1023;
        short8 v;
        #pragma unroll
        for (int j = 0; j < 8; ++j) v[j] = (short)f2bf(wfc1[(kk + j) * 128 + n]);
        *(short8*)&fc1T[base] = v;
    }
}

// ---------------- K1: per-patch conv1+pool1+conv2+pool2 ----------------------
__global__ __launch_bounds__(256, 2) void k1_feat(
    const float* __restrict__ x, const u16* __restrict__ w1p,
    const u16* __restrict__ w2p, const float* __restrict__ b1g,
    const float* __restrict__ b2g, u16* __restrict__ feat)
{
    __shared__ unsigned s2[40 * 44];     // dup-pair patch rows -4..35
    __shared__ u16 s_h1p[20 * 20 * 24];  // pool1, ring-padded, cell stride 24 u16
    __shared__ unsigned s_feat[512];     // swizzled packed features

    const int tid = threadIdx.x;
    const int lane = tid & 63;
    const int wv = tid >> 6;
    const int mm = lane & 15;
    const int bq = lane >> 4;
    const int blk = blockIdx.x;
    const int py = blk / 96, px = blk % 96;

    {   // zero: s2 pad rows + right pad cols (selective), s_h1p full (simple)
        uint4 z4 = {0, 0, 0, 0};
        for (int i = tid; i < 152; i += 256) {
            int dst;
            if (i < 88) { int r8 = i / 11, c4 = i % 11;
                          int row = (r8 < 4) ? r8 : 32 + r8; dst = row * 11 + c4; }
            else        { int j = i - 88; dst = (4 + (j >> 1)) * 11 + 9 + (j & 1); }
            ((uint4*)s2)[dst] = z4;
        }
        for (int i = tid; i < 1200; i += 256) ((uint4*)s_h1p)[i] = z4;
    }

    // conv1 weights + biases (L2-hot); w2f deferred until after conv1
    short8 w1f[5];
    #pragma unroll
    for (int s = 0; s < 5; ++s) w1f[s] = *(const short8*)&w1p[(s * 64 + lane) * 8];
    const float bias1 = b1g[mm], bias2 = b2g[mm];

    // fill s2 interior: 32 rows x 9 quad-groups
    for (int task = tid; task < 288; task += 256) {
        int ir = task / 9, g = task - ir * 9;
        int ic0 = g * 4 - 4;
        const float* xr = x + (py + ir) * 128 + px;
        float v[5];
        #pragma unroll
        for (int vi = 0; vi < 5; ++vi) {
            int ic = ic0 + vi;
            v[vi] = (ic >= 0 && ic < 32) ? xr[ic] : 0.f;
        }
        uint4 w;
        w.x = pkbf(v[0], v[1]);
        w.y = pkbf(v[1], v[2]);
        w.z = pkbf(v[2], v[3]);
        w.w = pkbf(v[3], v[4]);
        *(uint4*)&s2[(4 + ir) * 44 + g * 4] = w;
    }
    __syncthreads();

    union F { short8 s; unsigned u[4]; };
    const int dxq = (bq == 3) ? 0 : bq;

    // conv1: 4 independent acc chains; B-fragments share their first row with
    // the A-fragment's second row (register reuse, -30% conv1 LDS bytes).
    for (int qi = 0; qi < 4; ++qi) {
        int q = wv + qi * 4;
        const unsigned* p0 = &s2[(2 * q) * 44 + mm + dxq * 4];
        const unsigned* p1 = p0 + 16;
        f32x4 ac0 = {0, 0, 0, 0}, ac1 = {0, 0, 0, 0};
        f32x4 ac2 = {0, 0, 0, 0}, ac3 = {0, 0, 0, 0};

        auto stepAB = [&](const unsigned* P0, const unsigned* P1, int ra,
                          short8 w, bool last) {
            F fa0, fa1, fb0, fb1;
            fa0.u[0] = P0[ra];      fa0.u[1] = P0[ra + 2];
            fa0.u[2] = P0[ra + 44]; fa0.u[3] = P0[ra + 46];
            fa1.u[0] = P1[ra];      fa1.u[1] = P1[ra + 2];
            fa1.u[2] = P1[ra + 44]; fa1.u[3] = P1[ra + 46];
            fb0.u[0] = fa0.u[2];    fb0.u[1] = fa0.u[3];
            fb1.u[0] = fa1.u[2];    fb1.u[1] = fa1.u[3];
            if (!last) {
                fb0.u[2] = P0[ra + 88]; fb0.u[3] = P0[ra + 90];
                fb1.u[2] = P1[ra + 88]; fb1.u[3] = P1[ra + 90];
            } else {        // s=4: fb = {row9, row8} = fa halves swapped
                fb0.u[2] = fa0.u[0];    fb0.u[3] = fa0.u[1];
                fb1.u[2] = fa1.u[0];    fb1.u[3] = fa1.u[1];
            }
            ac0 = __builtin_amdgcn_mfma_f32_16x16x32_bf16(fa0.s, w, ac0, 0, 0, 0);
            ac2 = __builtin_amdgcn_mfma_f32_16x16x32_bf16(fa1.s, w, ac2, 0, 0, 0);
            ac1 = __builtin_amdgcn_mfma_f32_16x16x32_bf16(fb0.s, w, ac1, 0, 0, 0);
            ac3 = __builtin_amdgcn_mfma_f32_16x16x32_bf16(fb1.s, w, ac3, 0, 0, 0);
        };
        stepAB(p0,       p1,       0,  w1f[0], false);   // rows 0-2
        stepAB(p0,       p1,       88, w1f[1], false);   // rows 2-4
        stepAB(p0 + 176, p1 + 176, 0,  w1f[2], false);   // rows 4-6
        stepAB(p0 + 176, p1 + 176, 88, w1f[3], false);   // rows 6-8
        stepAB(p0 + 352, p1 + 352, 0,  w1f[4], true);    // rows 8,9 / 9,8

        #pragma unroll
        for (int h = 0; h < 2; ++h) {
            f32x4 aA = h ? ac2 : ac0, aB = h ? ac3 : ac1;
            float vr0, vr1;
            {
                float a0 = fmaxf(fmaxf(aA[0], aA[1]), fmaxf(aB[0], aB[1]));
                vr0 = fmaxf(a0 + bias1, 0.f);
                float a1 = fmaxf(fmaxf(aA[2], aA[3]), fmaxf(aB[2], aB[3]));
                vr1 = fmaxf(a1 + bias1, 0.f);
            }
            unsigned pw = pkbf(vr0, vr1);
            int pc = h * 8 + (bq << 1);
            int cb = ((2 + q) * 20 + (2 + pc)) * 24 + mm;
            s_h1p[cb] = (u16)pw;
            s_h1p[cb + 24] = (u16)(pw >> 16);
        }
    }
    __syncthreads();

    // conv2 weights loaded here (post-conv1) to cut conv1-phase reg pressure
    short8 w2f[13];
    #pragma unroll
    for (int s = 0; s < 13; ++s) w2f[s] = *(const short8*)&w2p[(s * 64 + lane) * 8];

    // conv2: both q-tiles (wv, wv+4) together -> 4 acc chains, rolling loads
    {
        const int q0 = wv, q1 = wv + 4;
        const int c8s = (bq & 1) * 8;
        const int baseA0 = ((2 * q0) * 20 + mm + (bq >> 1)) * 24 + c8s;
        const int baseA1 = ((2 * q1) * 20 + mm + (bq >> 1)) * 24 + c8s;
        const int baseB0 = baseA0 + 2 * 24;
        const int baseB1 = baseA1 + 2 * 24;
        const int c8C = (bq >> 1) * 8;
        const int yC0 = 2 * q0 + 3 * (bq & 1);
        const int yC1 = 2 * q1 + 3 * (bq & 1);
        f32x4 p0A = {0, 0, 0, 0}, p0B = {0, 0, 0, 0};
        f32x4 p1A = {0, 0, 0, 0}, p1B = {0, 0, 0, 0};

        short8 a0 = *(const short8*)&s_h1p[baseA0];
        short8 a1 = *(const short8*)&s_h1p[baseA1];
        #pragma unroll
        for (int s = 0; s < 5; ++s) {
            short8 n0 = *(const short8*)&s_h1p[baseA0 + (s + 1) * 480];
            short8 n1 = *(const short8*)&s_h1p[baseA1 + (s + 1) * 480];
            p0A = __builtin_amdgcn_mfma_f32_16x16x32_bf16(a0, w2f[s], p0A, 0, 0, 0);
            p1A = __builtin_amdgcn_mfma_f32_16x16x32_bf16(a1, w2f[s], p1A, 0, 0, 0);
            p0B = __builtin_amdgcn_mfma_f32_16x16x32_bf16(n0, w2f[s], p0B, 0, 0, 0);
            p1B = __builtin_amdgcn_mfma_f32_16x16x32_bf16(n1, w2f[s], p1B, 0, 0, 0);
            a0 = n0; a1 = n1;
        }
        a0 = *(const short8*)&s_h1p[baseB0];
        a1 = *(const short8*)&s_h1p[baseB1];
        #pragma unroll
        for (int s = 0; s < 5; ++s) {
            short8 n0 = *(const short8*)&s_h1p[baseB0 + (s + 1) * 480];
            short8 n1 = *(const short8*)&s_h1p[baseB1 + (s + 1) * 480];
            p0A = __builtin_amdgcn_mfma_f32_16x16x32_bf16(a0, w2f[5 + s], p0A, 0, 0, 0);
            p1A = __builtin_amdgcn_mfma_f32_16x16x32_bf16(a1, w2f[5 + s], p1A, 0, 0, 0);
            p0B = __builtin_amdgcn_mfma_f32_16x16x32_bf16(n0, w2f[5 + s], p0B, 0, 0, 0);
            p1B = __builtin_amdgcn_mfma_f32_16x16x32_bf16(n1, w2f[5 + s], p1B, 0, 0, 0);
            a0 = n0; a1 = n1;
        }
        {
            int y00 = yC0, y10 = (yC1 > 19) ? 19 : yC1;
            a0 = *(const short8*)&s_h1p[(y00 * 20 + mm + 4) * 24 + c8C];
            a1 = *(const short8*)&s_h1p[(y10 * 20 + mm + 4) * 24 + c8C];
        }
        #pragma unroll
        for (int s = 0; s < 3; ++s) {
            int y0n = yC0 + s + 1; if (y0n > 19) y0n = 19;
            int y1n = yC1 + s + 1; if (y1n > 19) y1n = 19;
            short8 n0 = *(const short8*)&s_h1p[(y0n * 20 + mm + 4) * 24 + c8C];
            short8 n1 = *(const short8*)&s_h1p[(y1n * 20 + mm + 4) * 24 + c8C];
            p0A = __builtin_amdgcn_mfma_f32_16x16x32_bf16(a0, w2f[10 + s], p0A, 0, 0, 0);
            p1A = __builtin_amdgcn_mfma_f32_16x16x32_bf16(a1, w2f[10 + s], p1A, 0, 0, 0);
            p0B = __builtin_amdgcn_mfma_f32_16x16x32_bf16(n0, w2f[10 + s], p0B, 0, 0, 0);
            p1B = __builtin_amdgcn_mfma_f32_16x16x32_bf16(n1, w2f[10 + s], p1B, 0, 0, 0);
            a0 = n0; a1 = n1;
        }
        #pragma unroll
        for (int pi = 0; pi < 2; ++pi) {
            f32x4 aA = pi ? p1A : p0A, aB = pi ? p1B : p0B;
            int q = pi ? q1 : q0;
            float v0, v1;
            {
                float a = fmaxf(fmaxf(aA[0], aA[1]), fmaxf(aB[0], aB[1]));
                v0 = fmaxf(a + bias2, 0.f);
                float b = fmaxf(fmaxf(aA[2], aA[3]), fmaxf(aB[2], aB[3]));
                v1 = fmaxf(b + bias2, 0.f);
            }
            unsigned dwv = pkbf(v0, v1);
            s_feat[mm * 32 + ((q * 4 + bq) ^ mm)] = dwv;   // XOR-swizzled
        }
    }
    __syncthreads();

    {   // coalesced feature writeout (bf16), unswizzle
        int ci = tid >> 4, t = tid & 15;
        uint2 v;
        v.x = s_feat[ci * 32 + ((2 * t) ^ ci)];
        v.y = s_feat[ci * 32 + ((2 * t + 1) ^ ci)];
        *(uint2*)&feat[blk * 1024 + tid * 4] = v;
    }
}

// ---------------- K2: fc1 (+relu) fused with fc2 -> heat ---------------------
// 288 blocks: (b%144) = 64-patch tile, (b/144) = n-half (64 of 128).
__global__ __launch_bounds__(256) void k2_fc(
    const u16* __restrict__ feat, const u16* __restrict__ fc1T,
    const float* __restrict__ bfc1, const float* __restrict__ wfc2,
    float* __restrict__ out)
{
    __shared__ u16 sA[64 * 136];
    __shared__ u16 sB[64 * 136];
    const int tid = threadIdx.x;
    const int lane = tid & 63;
    const int wv = tid >> 6;
    const int mm = lane & 15;
    const int bq = lane >> 4;
    const int p0 = (blockIdx.x % 144) * 64;
    const int n0 = (blockIdx.x / 144) * 64;

    f32x4 acc[4];
    #pragma unroll
    for (int i = 0; i < 4; ++i) acc[i] = (f32x4){0, 0, 0, 0};

    for (int kt = 0; kt < 8; ++kt) {
        for (int i = tid; i < 1024; i += 256) {         // A tile 64x128
            int row = i >> 4, ch = i & 15;
            *(short8*)&sA[row * 136 + ch * 8] =
                *(const short8*)&feat[(p0 + row) * 1024 + kt * 128 + ch * 8];
        }
        for (int i = tid; i < 1024; i += 256) {         // B tile [n][k] 64x128
            int row = i >> 4, ch = i & 15;
            *(short8*)&sB[row * 136 + ch * 8] =
                *(const short8*)&fc1T[(n0 + row) * 1024 + kt * 128 + ch * 8];
        }
        __syncthreads();
        #pragma unroll
        for (int ks = 0; ks < 4; ++ks) {
            short8 aF = *(const short8*)&sA[(wv * 16 + mm) * 136 + ks * 32 + bq * 8];
            #pragma unroll
            for (int nt = 0; nt < 4; ++nt) {
                short8 bF = *(const short8*)&sB[(nt * 16 + mm) * 136 + ks * 32 + bq * 8];
                acc[nt] = __builtin_amdgcn_mfma_f32_16x16x32_bf16(aF, bF, acc[nt], 0, 0, 0);
            }
        }
        __syncthreads();
    }

    float qs[4] = {0, 0, 0, 0};
    #pragma unroll
    for (int nt = 0; nt < 4; ++nt) {
        int n = n0 + nt * 16 + mm;
        float bb = bfc1[n], wf = wfc2[n];
        #pragma unroll
        for (int r = 0; r < 4; ++r) {
            float f = fmaxf(acc[nt][r] + bb, 0.f);
            qs[r] += f * wf;
        }
    }
    #pragma unroll
    for (int r = 0; r < 4; ++r) {             // reduce across the 16 n-lanes
        float v = qs[r];
        v += __shfl_xor(v, 1);
        v += __shfl_xor(v, 2);
        v += __shfl_xor(v, 4);
        v += __shfl_xor(v, 8);
        qs[r] = v;
    }
    if (mm == 0) {
        #pragma unroll
        for (int r = 0; r < 4; ++r) {
            int p = p0 + wv * 16 + bq * 4 + r;
            int qy = p / 96, qx = p % 96;
            atomicAdd(&out[(16 + qy) * 128 + (16 + qx)], qs[r]);
        }
    }
}

// ---------------- launch -----------------------------------------------------
extern "C" void kernel_launch(void* const* d_in, const int* in_sizes, int n_in,
                              void* d_out, int out_size, void* d_ws, size_t ws_size,
                              hipStream_t stream)
{
    const float* x     = (const float*)d_in[0];
    const float* z     = (const float*)d_in[1];
    const float* w1    = (const float*)d_in[2];
    const float* b1    = (const float*)d_in[3];
    const float* w2    = (const float*)d_in[4];
    const float* b2    = (const float*)d_in[5];
    const float* wfc1  = (const float*)d_in[6];
    const float* bfc1  = (const float*)d_in[7];
    const float* wpose = (const float*)d_in[8];
    const float* bpose = (const float*)d_in[9];
    const float* wfc2  = (const float*)d_in[10];
    const float* bfc2  = (const float*)d_in[11];
    float* out = (float*)d_out;

    char* ws = (char*)d_ws;
    u16*   w1p  = (u16*)(ws + 0);        // 5120 B
    u16*   w2p  = (u16*)(ws + 8192);     // 13312 B
    u16*   fc1T = (u16*)(ws + 24576);    // 262144 B
    u16*   feat = (u16*)(ws + 294912);   // 18874368 B

    hipLaunchKernelGGL(k0_prep, dim3(64), dim3(256), 0, stream,
                       z, w1, w2, wfc1, wpose, bpose, wfc2, bfc2,
                       out, w1p, w2p, fc1T);
    hipLaunchKernelGGL(k1_feat, dim3(9216), dim3(256), 0, stream,
                       x, w1p, w2p, b1, b2, feat);
    hipLaunchKernelGGL(k2_fc, dim3(288), dim3(256), 0, stream,
                       feat, fc1T, bfc1, wfc2, out);
}

// Round 13
// 95.665 us; speedup vs baseline: 1.0661x; 1.0661x over previous
//
#include <hip/hip_runtime.h>

typedef __attribute__((ext_vector_type(8))) short short8;
typedef __attribute__((ext_vector_type(4))) float f32x4;
typedef unsigned short u16;

__device__ __forceinline__ u16 f2bf(float f) {
    unsigned u = __builtin_bit_cast(unsigned, f);
    unsigned r = u + 0x7fffu + ((u >> 16) & 1u);
    return (u16)(r >> 16);
}
__device__ __forceinline__ unsigned pkbf(float lo, float hi) {
    unsigned r;
    asm("v_cvt_pk_bf16_f32 %0, %1, %2" : "=v"(r) : "v"(lo), "v"(hi));
    return r;
}

// ---------------- K0: prep (out=cpose/0, pack weights) -----------------------
__global__ __launch_bounds__(256) void k0_prep(
    const float* __restrict__ z, const float* __restrict__ w1,
    const float* __restrict__ w2, const float* __restrict__ wfc1,
    const float* __restrict__ wpose, const float* __restrict__ bpose,
    const float* __restrict__ wfc2, const float* __restrict__ bfc2,
    float* __restrict__ out, u16* __restrict__ w1p, u16* __restrict__ w2p,
    u16* __restrict__ fc1T)
{
    int gt = blockIdx.x * 256 + threadIdx.x;   // 0..16383

    {   // pose branch + b_fc2 constant (redundant per thread), init heat
        float zz = z[0];
        float s = bfc2[0];
        #pragma unroll
        for (int j = 0; j < 16; ++j) {
            float p = fmaxf(zz * wpose[j] + bpose[j], 0.f);
            s += p * wfc2[128 + j];
        }
        int y = gt >> 7, x = gt & 127;
        bool interior = (y >= 16) && (y < 112) && (x >= 16) && (x < 112);
        out[gt] = interior ? s : 0.f;
    }

    if (gt < 2560) {                           // w1 pack: [5 ksteps][64 lanes][8]
        int l = (gt >> 3) & 63, j = gt & 7, s = gt >> 9;
        int o = l & 15, bq = l >> 4;
        u16 v = 0;
        if (bq < 3) {
            int dx = bq * 4 + (j & 3);
            int dy = -1;
            if (s < 4) dy = 2 * s + (j >> 2);
            else if (j < 4) dy = 8;
            if (dy >= 0 && dx <= 8) v = f2bf(w1[o * 81 + dy * 9 + dx]);
        }
        w1p[gt] = v;
    }
    if (gt < 6656) {                           // w2 pack: [13][64][8]
        int l = (gt >> 3) & 63, j = gt & 7, s = gt >> 9;
        int o = l & 15, bq = l >> 4;
        int dy, dx, c8; bool valid = true;
        if (s < 5)       { dy = s;     dx = bq >> 1;       c8 = bq & 1; }
        else if (s < 10) { dy = s - 5; dx = 2 + (bq >> 1); c8 = bq & 1; }
        else { dy = (s - 10) + 3 * (bq & 1); dx = 4; c8 = bq >> 1; valid = (dy <= 4); }
        int ci = c8 * 8 + j;
        w2p[gt] = valid ? f2bf(w2[o * 400 + ci * 25 + dy * 5 + dx]) : (u16)0;
    }
    {                                          // fc1 transpose-pack: [128 n][1024 k]
        int base = gt * 8;
        int n = base >> 10, kk = base & 1023;
        short8 v;
        #pragma unroll
        for (int j = 0; j < 8; ++j) v[j] = (short)f2bf(wfc1[(kk + j) * 128 + n]);
        *(short8*)&fc1T[base] = v;
    }
}

// ---------------- K1: per-patch conv1+pool1+conv2+pool2 ----------------------
__global__ __launch_bounds__(256, 2) void k1_feat(
    const float* __restrict__ x, const u16* __restrict__ w1p,
    const u16* __restrict__ w2p, const float* __restrict__ b1g,
    const float* __restrict__ b2g, u16* __restrict__ feat)
{
    __shared__ unsigned s2[40 * 44];     // dup-pair patch rows -4..35
    __shared__ u16 s_h1p[20 * 20 * 24];  // pool1, ring-padded, cell stride 24 u16
    __shared__ unsigned s_feat[512];     // swizzled packed features

    const int tid = threadIdx.x;
    const int lane = tid & 63;
    const int wv = tid >> 6;
    const int mm = lane & 15;
    const int bq = lane >> 4;
    const int blk = blockIdx.x;
    const int py = blk / 96, px = blk % 96;

    {   // zero: s2 pad rows + right pad cols; s_h1p RING cells only (interior
        // cells are fully overwritten by conv1; slots 16-23 never read)
        uint4 z4 = {0, 0, 0, 0};
        for (int i = tid; i < 152; i += 256) {
            int dst;
            if (i < 88) { int r8 = i / 11, c4 = i % 11;
                          int row = (r8 < 4) ? r8 : 32 + r8; dst = row * 11 + c4; }
            else        { int j = i - 88; dst = (4 + (j >> 1)) * 11 + 9 + (j & 1); }
            ((uint4*)s2)[dst] = z4;
        }
        for (int i = tid; i < 288; i += 256) {
            int c = i >> 1, half = i & 1;
            int y, xx;
            if (c < 80) { int top = (c >= 40); int cc = c - top * 40;
                          y = top * 18 + cc / 20; xx = cc % 20; }
            else { int jj = c - 80; y = 2 + (jj >> 2); int sel = jj & 3;
                   xx = (sel < 2) ? sel : 16 + sel; }
            *(uint4*)&s_h1p[(y * 20 + xx) * 24 + half * 8] = z4;
        }
    }

    // conv1 weights + biases (L2-hot); w2f deferred until after conv1
    short8 w1f[5];
    #pragma unroll
    for (int s = 0; s < 5; ++s) w1f[s] = *(const short8*)&w1p[(s * 64 + lane) * 8];
    const float bias1 = b1g[mm], bias2 = b2g[mm];

    // fill s2 interior: 32 rows x 9 quad-groups
    for (int task = tid; task < 288; task += 256) {
        int ir = task / 9, g = task - ir * 9;
        int ic0 = g * 4 - 4;
        const float* xr = x + (py + ir) * 128 + px;
        float v[5];
        #pragma unroll
        for (int vi = 0; vi < 5; ++vi) {
            int ic = ic0 + vi;
            v[vi] = (ic >= 0 && ic < 32) ? xr[ic] : 0.f;
        }
        uint4 w;
        w.x = pkbf(v[0], v[1]);
        w.y = pkbf(v[1], v[2]);
        w.z = pkbf(v[2], v[3]);
        w.w = pkbf(v[3], v[4]);
        *(uint4*)&s2[(4 + ir) * 44 + g * 4] = w;
    }
    __syncthreads();

    union F { short8 s; unsigned u[4]; };
    const int dxq = (bq == 3) ? 0 : bq;

    // conv1: 4 independent acc chains; 3 bases/chain so every ds_read2 offset
    // pair fits the 255-dword immediate (no per-read v_add address math)
    for (int qi = 0; qi < 4; ++qi) {
        int q = wv + qi * 4;
        const unsigned* p0 = &s2[(2 * q) * 44 + mm + dxq * 4];
        const unsigned* p1 = p0 + 16;
        f32x4 ac0 = {0, 0, 0, 0}, ac1 = {0, 0, 0, 0};
        f32x4 ac2 = {0, 0, 0, 0}, ac3 = {0, 0, 0, 0};

        auto step = [&](const unsigned* P0, const unsigned* P1,
                        int ra, int blo, int bhi, short8 w) {
            F fa0, fa1, fb0, fb1;
            fa0.u[0] = P0[ra];      fa0.u[1] = P0[ra + 2];
            fa0.u[2] = P0[ra + 44]; fa0.u[3] = P0[ra + 46];
            fa1.u[0] = P1[ra];      fa1.u[1] = P1[ra + 2];
            fa1.u[2] = P1[ra + 44]; fa1.u[3] = P1[ra + 46];
            fb0.u[0] = P0[blo];     fb0.u[1] = P0[blo + 2];
            fb0.u[2] = P0[bhi];     fb0.u[3] = P0[bhi + 2];
            fb1.u[0] = P1[blo];     fb1.u[1] = P1[blo + 2];
            fb1.u[2] = P1[bhi];     fb1.u[3] = P1[bhi + 2];
            ac0 = __builtin_amdgcn_mfma_f32_16x16x32_bf16(fa0.s, w, ac0, 0, 0, 0);
            ac2 = __builtin_amdgcn_mfma_f32_16x16x32_bf16(fa1.s, w, ac2, 0, 0, 0);
            ac1 = __builtin_amdgcn_mfma_f32_16x16x32_bf16(fb0.s, w, ac1, 0, 0, 0);
            ac3 = __builtin_amdgcn_mfma_f32_16x16x32_bf16(fb1.s, w, ac3, 0, 0, 0);
        };
        step(p0,       p1,       0,  44, 88,  w1f[0]);   // rows 0-2
        step(p0,       p1,       88, 132, 176, w1f[1]);  // rows 2-4
        step(p0 + 176, p1 + 176, 0,  44, 88,  w1f[2]);   // rows 4-6
        step(p0 + 176, p1 + 176, 88, 132, 176, w1f[3]);  // rows 6-8
        step(p0 + 352, p1 + 352, 0,  44, 0,   w1f[4]);   // rows 8,9 / 9,8

        #pragma unroll
        for (int h = 0; h < 2; ++h) {
            f32x4 aA = h ? ac2 : ac0, aB = h ? ac3 : ac1;
            float vr0, vr1;
            {
                float a0 = fmaxf(fmaxf(aA[0], aA[1]), fmaxf(aB[0], aB[1]));
                vr0 = fmaxf(a0 + bias1, 0.f);
                float a1 = fmaxf(fmaxf(aA[2], aA[3]), fmaxf(aB[2], aB[3]));
                vr1 = fmaxf(a1 + bias1, 0.f);
            }
            unsigned pw = pkbf(vr0, vr1);
            int pc = h * 8 + (bq << 1);
            int cb = ((2 + q) * 20 + (2 + pc)) * 24 + mm;
            s_h1p[cb] = (u16)pw;
            s_h1p[cb + 24] = (u16)(pw >> 16);
        }
    }
    __syncthreads();

    // conv2 weights loaded here (post-conv1) to cut conv1-phase reg pressure
    short8 w2f[13];
    #pragma unroll
    for (int s = 0; s < 13; ++s) w2f[s] = *(const short8*)&w2p[(s * 64 + lane) * 8];

    // conv2: both q-tiles (wv, wv+4) together -> 4 acc chains, rolling loads
    {
        const int q0 = wv, q1 = wv + 4;
        const int c8s = (bq & 1) * 8;
        const int baseA0 = ((2 * q0) * 20 + mm + (bq >> 1)) * 24 + c8s;
        const int baseA1 = ((2 * q1) * 20 + mm + (bq >> 1)) * 24 + c8s;
        const int baseB0 = baseA0 + 2 * 24;
        const int baseB1 = baseA1 + 2 * 24;
        const int c8C = (bq >> 1) * 8;
        const int yC0 = 2 * q0 + 3 * (bq & 1);
        const int yC1 = 2 * q1 + 3 * (bq & 1);
        f32x4 p0A = {0, 0, 0, 0}, p0B = {0, 0, 0, 0};
        f32x4 p1A = {0, 0, 0, 0}, p1B = {0, 0, 0, 0};

        short8 a0 = *(const short8*)&s_h1p[baseA0];
        short8 a1 = *(const short8*)&s_h1p[baseA1];
        #pragma unroll
        for (int s = 0; s < 5; ++s) {
            short8 n0 = *(const short8*)&s_h1p[baseA0 + (s + 1) * 480];
            short8 n1 = *(const short8*)&s_h1p[baseA1 + (s + 1) * 480];
            p0A = __builtin_amdgcn_mfma_f32_16x16x32_bf16(a0, w2f[s], p0A, 0, 0, 0);
            p1A = __builtin_amdgcn_mfma_f32_16x16x32_bf16(a1, w2f[s], p1A, 0, 0, 0);
            p0B = __builtin_amdgcn_mfma_f32_16x16x32_bf16(n0, w2f[s], p0B, 0, 0, 0);
            p1B = __builtin_amdgcn_mfma_f32_16x16x32_bf16(n1, w2f[s], p1B, 0, 0, 0);
            a0 = n0; a1 = n1;
        }
        a0 = *(const short8*)&s_h1p[baseB0];
        a1 = *(const short8*)&s_h1p[baseB1];
        #pragma unroll
        for (int s = 0; s < 5; ++s) {
            short8 n0 = *(const short8*)&s_h1p[baseB0 + (s + 1) * 480];
            short8 n1 = *(const short8*)&s_h1p[baseB1 + (s + 1) * 480];
            p0A = __builtin_amdgcn_mfma_f32_16x16x32_bf16(a0, w2f[5 + s], p0A, 0, 0, 0);
            p1A = __builtin_amdgcn_mfma_f32_16x16x32_bf16(a1, w2f[5 + s], p1A, 0, 0, 0);
            p0B = __builtin_amdgcn_mfma_f32_16x16x32_bf16(n0, w2f[5 + s], p0B, 0, 0, 0);
            p1B = __builtin_amdgcn_mfma_f32_16x16x32_bf16(n1, w2f[5 + s], p1B, 0, 0, 0);
            a0 = n0; a1 = n1;
        }
        {
            int y00 = yC0, y10 = (yC1 > 19) ? 19 : yC1;
            a0 = *(const short8*)&s_h1p[(y00 * 20 + mm + 4) * 24 + c8C];
            a1 = *(const short8*)&s_h1p[(y10 * 20 + mm + 4) * 24 + c8C];
        }
        #pragma unroll
        for (int s = 0; s < 3; ++s) {
            int y0n = yC0 + s + 1; if (y0n > 19) y0n = 19;
            int y1n = yC1 + s + 1; if (y1n > 19) y1n = 19;
            short8 n0 = *(const short8*)&s_h1p[(y0n * 20 + mm + 4) * 24 + c8C];
            short8 n1 = *(const short8*)&s_h1p[(y1n * 20 + mm + 4) * 24 + c8C];
            p0A = __builtin_amdgcn_mfma_f32_16x16x32_bf16(a0, w2f[10 + s], p0A, 0, 0, 0);
            p1A = __builtin_amdgcn_mfma_f32_16x16x32_bf16(a1, w2f[10 + s], p1A, 0, 0, 0);
            p0B = __builtin_amdgcn_mfma_f32_16x16x32_bf16(n0, w2f[10 + s], p0B, 0, 0, 0);
            p1B = __builtin_amdgcn_mfma_f32_16x16x32_bf16(n1, w2f[10 + s], p1B, 0, 0, 0);
            a0 = n0; a1 = n1;
        }
        #pragma unroll
        for (int pi = 0; pi < 2; ++pi) {
            f32x4 aA = pi ? p1A : p0A, aB = pi ? p1B : p0B;
            int q = pi ? q1 : q0;
            float v0, v1;
            {
                float a = fmaxf(fmaxf(aA[0], aA[1]), fmaxf(aB[0], aB[1]));
                v0 = fmaxf(a + bias2, 0.f);
                float b = fmaxf(fmaxf(aA[2], aA[3]), fmaxf(aB[2], aB[3]));
                v1 = fmaxf(b + bias2, 0.f);
            }
            unsigned dwv = pkbf(v0, v1);
            s_feat[mm * 32 + ((q * 4 + bq) ^ mm)] = dwv;   // XOR-swizzled
        }
    }
    __syncthreads();

    {   // coalesced feature writeout (bf16), unswizzle
        int ci = tid >> 4, t = tid & 15;
        uint2 v;
        v.x = s_feat[ci * 32 + ((2 * t) ^ ci)];
        v.y = s_feat[ci * 32 + ((2 * t + 1) ^ ci)];
        *(uint2*)&feat[blk * 1024 + tid * 4] = v;
    }
}

// ---------------- K2: fc1 (+relu) fused with fc2 -> heat ---------------------
// 576 blocks: (b%144) = 64-patch tile, (b/144) = n-quarter (32 of 128).
__global__ __launch_bounds__(256) void k2_fc(
    const u16* __restrict__ feat, const u16* __restrict__ fc1T,
    const float* __restrict__ bfc1, const float* __restrict__ wfc2,
    float* __restrict__ out)
{
    __shared__ u16 sA[64 * 136];
    __shared__ u16 sB[32 * 136];
    const int tid = threadIdx.x;
    const int lane = tid & 63;
    const int wv = tid >> 6;
    const int mm = lane & 15;
    const int bq = lane >> 4;
    const int p0 = (blockIdx.x % 144) * 64;
    const int n0 = (blockIdx.x / 144) * 32;

    f32x4 acc[2];
    acc[0] = (f32x4){0, 0, 0, 0};
    acc[1] = (f32x4){0, 0, 0, 0};

    for (int kt = 0; kt < 8; ++kt) {
        for (int i = tid; i < 1024; i += 256) {         // A tile 64x128
            int row = i >> 4, ch = i & 15;
            *(short8*)&sA[row * 136 + ch * 8] =
                *(const short8*)&feat[(p0 + row) * 1024 + kt * 128 + ch * 8];
        }
        for (int i = tid; i < 512; i += 256) {          // B tile [n][k] 32x128
            int row = i >> 4, ch = i & 15;
            *(short8*)&sB[row * 136 + ch * 8] =
                *(const short8*)&fc1T[(n0 + row) * 1024 + kt * 128 + ch * 8];
        }
        __syncthreads();
        #pragma unroll
        for (int ks = 0; ks < 4; ++ks) {
            short8 aF = *(const short8*)&sA[(wv * 16 + mm) * 136 + ks * 32 + bq * 8];
            #pragma unroll
            for (int nt = 0; nt < 2; ++nt) {
                short8 bF = *(const short8*)&sB[(nt * 16 + mm) * 136 + ks * 32 + bq * 8];
                acc[nt] = __builtin_amdgcn_mfma_f32_16x16x32_bf16(aF, bF, acc[nt], 0, 0, 0);
            }
        }
        __syncthreads();
    }

    float qs[4] = {0, 0, 0, 0};
    #pragma unroll
    for (int nt = 0; nt < 2; ++nt) {
        int n = n0 + nt * 16 + mm;
        float bb = bfc1[n], wf = wfc2[n];
        #pragma unroll
        for (int r = 0; r < 4; ++r) {
            float f = fmaxf(acc[nt][r] + bb, 0.f);
            qs[r] += f * wf;
        }
    }
    #pragma unroll
    for (int r = 0; r < 4; ++r) {             // reduce across the 16 n-lanes
        float v = qs[r];
        v += __shfl_xor(v, 1);
        v += __shfl_xor(v, 2);
        v += __shfl_xor(v, 4);
        v += __shfl_xor(v, 8);
        qs[r] = v;
    }
    if (mm == 0) {
        #pragma unroll
        for (int r = 0; r < 4; ++r) {
            int p = p0 + wv * 16 + bq * 4 + r;
            int qy = p / 96, qx = p % 96;
            atomicAdd(&out[(16 + qy) * 128 + (16 + qx)], qs[r]);
        }
    }
}

// ---------------- launch -----------------------------------------------------
extern "C" void kernel_launch(void* const* d_in, const int* in_sizes, int n_in,
                              void* d_out, int out_size, void* d_ws, size_t ws_size,
                              hipStream_t stream)
{
    const float* x     = (const float*)d_in[0];
    const float* z     = (const float*)d_in[1];
    const float* w1    = (const float*)d_in[2];
    const float* b1    = (const float*)d_in[3];
    const float* w2    = (const float*)d_in[4];
    const float* b2    = (const float*)d_in[5];
    const float* wfc1  = (const float*)d_in[6];
    const float* bfc1  = (const float*)d_in[7];
    const float* wpose = (const float*)d_in[8];
    const float* bpose = (const float*)d_in[9];
    const float* wfc2  = (const float*)d_in[10];
    const float* bfc2  = (const float*)d_in[11];
    float* out = (float*)d_out;

    char* ws = (char*)d_ws;
    u16*   w1p  = (u16*)(ws + 0);        // 5120 B
    u16*   w2p  = (u16*)(ws + 8192);     // 13312 B
    u16*   fc1T = (u16*)(ws + 24576);    // 262144 B
    u16*   feat = (u16*)(ws + 294912);   // 18874368 B

    hipLaunchKernelGGL(k0_prep, dim3(64), dim3(256), 0, stream,
                       z, w1, w2, wfc1, wpose, bpose, wfc2, bfc2,
                       out, w1p, w2p, fc1T);
    hipLaunchKernelGGL(k1_feat, dim3(9216), dim3(256), 0, stream,
                       x, w1p, w2p, b1, b2, feat);
    hipLaunchKernelGGL(k2_fc, dim3(576), dim3(256), 0, stream,
                       feat, fc1T, bfc1, wfc2, out);
}